// Round 3
// baseline (343.077 us; speedup 1.0000x reference)
//
#include <hip/hip_runtime.h>

// out[i][d] = params[idx[i]] * xs[i][d];  N=4194304, D=8, V=1048576
//
// Theory (round 3): the ~85us floor is the params random-gather path.
// Streaming traffic thrashes the 4MB params table out of each XCD's 4MB L2,
// so 4M random gathers are served by the slow L3/fabric random-line path.
// Fix: cache-policy separation.
//   - streams (xs, idx, out): raw buffer ops with cpol = nt|sc1 (18)
//     -> no L2 allocation (device scope), evict-first in L3
//   - params: plain loads, normal policy -> table stays L2-resident,
//     gathers become ~200cyc L2 hits.
// Policy bits never change values -> correctness unaffected.
// Buffer num_records gives HW bounds-checking (OOB load=0, store dropped),
// so no tail branch is needed.

typedef float f32x4 __attribute__((ext_vector_type(4)));
typedef int   i32x4 __attribute__((ext_vector_type(4)));

// CK-style raw buffer intrinsics (compiler tracks these as loads -> waitcnt ok)
__device__ f32x4 buf_load_x4(i32x4 rsrc, int voffset, int soffset, int cpol)
    __asm("llvm.amdgcn.raw.buffer.load.v4f32");
__device__ int   buf_load_i32(i32x4 rsrc, int voffset, int soffset, int cpol)
    __asm("llvm.amdgcn.raw.buffer.load.i32");
__device__ void  buf_store_x4(f32x4 data, i32x4 rsrc, int voffset, int soffset, int cpol)
    __asm("llvm.amdgcn.raw.buffer.store.v4f32");

// gfx950 cache policy bits in aux operand: sc0=1, nt=2, dlc=4, sc1=16
#define CPOL_STREAM 18   // nt | sc1 : non-temporal, device scope (skip L2 alloc)

__device__ __forceinline__ i32x4 make_rsrc(const void* p, unsigned bytes) {
    unsigned long long a = (unsigned long long)p;
    i32x4 r;
    r.x = (int)(a & 0xFFFFFFFFull);
    r.y = (int)(a >> 32);        // stride = 0
    r.z = (int)bytes;            // num_records (bytes, stride==0)
    r.w = 0x00020000;            // raw untyped dword access
    return r;
}

__global__ __launch_bounds__(256) void spvar_kernel(
    const float* __restrict__ xs,
    const int*   __restrict__ idx,
    const float* __restrict__ params,
    float*       __restrict__ out,
    int nrows, int stride)   // stride = gridDim.x * blockDim.x
{
    const i32x4 rx = make_rsrc(xs,  (unsigned)nrows * 32u);
    const i32x4 ri = make_rsrc(idx, (unsigned)nrows * 4u);
    const i32x4 ro = make_rsrc(out, (unsigned)nrows * 32u);

    const int t = blockIdx.x * blockDim.x + threadIdx.x;
    const int r0 = t;
    const int r1 = t + stride;
    const int r2 = t + 2 * stride;
    const int r3 = t + 3 * stride;

    // 4 independent idx loads (stream policy)
    const int i0 = buf_load_i32(ri, r0 * 4, 0, CPOL_STREAM);
    const int i1 = buf_load_i32(ri, r1 * 4, 0, CPOL_STREAM);
    const int i2 = buf_load_i32(ri, r2 * 4, 0, CPOL_STREAM);
    const int i3 = buf_load_i32(ri, r3 * 4, 0, CPOL_STREAM);

    // 8 xs loads (stream policy) — independent of the gather chain
    f32x4 a0 = buf_load_x4(rx, r0 * 32,      0, CPOL_STREAM);
    f32x4 b0 = buf_load_x4(rx, r0 * 32 + 16, 0, CPOL_STREAM);
    f32x4 a1 = buf_load_x4(rx, r1 * 32,      0, CPOL_STREAM);
    f32x4 b1 = buf_load_x4(rx, r1 * 32 + 16, 0, CPOL_STREAM);
    f32x4 a2 = buf_load_x4(rx, r2 * 32,      0, CPOL_STREAM);
    f32x4 b2 = buf_load_x4(rx, r2 * 32 + 16, 0, CPOL_STREAM);
    f32x4 a3 = buf_load_x4(rx, r3 * 32,      0, CPOL_STREAM);
    f32x4 b3 = buf_load_x4(rx, r3 * 32 + 16, 0, CPOL_STREAM);

    // 4 param gathers — NORMAL policy: the only L2-allocating traffic.
    // OOB rows have idx=0 (buffer load returned 0) -> params[0], harmless.
    const float p0 = params[i0];
    const float p1 = params[i1];
    const float p2 = params[i2];
    const float p3 = params[i3];

    a0 *= p0; b0 *= p0;
    a1 *= p1; b1 *= p1;
    a2 *= p2; b2 *= p2;
    a3 *= p3; b3 *= p3;

    // stores (stream policy); OOB stores dropped by HW bounds check
    buf_store_x4(a0, ro, r0 * 32,      0, CPOL_STREAM);
    buf_store_x4(b0, ro, r0 * 32 + 16, 0, CPOL_STREAM);
    buf_store_x4(a1, ro, r1 * 32,      0, CPOL_STREAM);
    buf_store_x4(b1, ro, r1 * 32 + 16, 0, CPOL_STREAM);
    buf_store_x4(a2, ro, r2 * 32,      0, CPOL_STREAM);
    buf_store_x4(b2, ro, r2 * 32 + 16, 0, CPOL_STREAM);
    buf_store_x4(a3, ro, r3 * 32,      0, CPOL_STREAM);
    buf_store_x4(b3, ro, r3 * 32 + 16, 0, CPOL_STREAM);
}

extern "C" void kernel_launch(void* const* d_in, const int* in_sizes, int n_in,
                              void* d_out, int out_size, void* d_ws, size_t ws_size,
                              hipStream_t stream) {
    const float* xs     = (const float*)d_in[0];   // [N, 8] f32
    const int*   idx    = (const int*)d_in[1];     // [N] int32 (jax x64 off)
    const float* params = (const float*)d_in[2];   // [V, 1] f32

    const int nrows = out_size / 8;                // N (out_size is f32 ELEMENTS, D=8)
    const int block = 256;
    const int rows_per_thread = 4;
    const int grid = (nrows + block * rows_per_thread - 1) / (block * rows_per_thread);
    const int stride = grid * block;

    spvar_kernel<<<grid, block, 0, stream>>>(
        xs, idx, params, (float*)d_out, nrows, stride);
}

// Round 4
// 268.193 us; speedup vs baseline: 1.2792x; 1.2792x over previous
//
#include <hip/hip_runtime.h>

// out[i][d] = params[idx[i]] * xs[i][d];  N=4194304, D=8, V=1048576
//
// Round 4: two-phase decomposition, plain cache policies everywhere
// (nt loads were neutral, nt|sc1 stores doubled WRITE_SIZE in round 3).
//
// Phase 1 (spvar_gather): p[i] = params[idx[i]] -> dense f32 workspace.
//   Pure gather stress: only 32 MB of streaming traffic competing, so the
//   4 MB params table can be L2-resident. 4 rows/thread, dense i32x4 idx
//   loads, dense f32x4 stores.
// Phase 2 (spvar_scale): out[i][:] = p[i] * xs[i][:].
//   Pure 3-stream elementwise (16 + 128 -> 128 MB), RMSNorm-shaped;
//   expect ~5 TB/s.
//
// Each phase profiles separately -> decisive attribution of the ~85us
// fused floor to either the gather mix or the stream ceiling.
// Fallback: fused kernel if workspace is too small.

typedef float f32x4 __attribute__((ext_vector_type(4)));
typedef int   i32x4 __attribute__((ext_vector_type(4)));

__global__ __launch_bounds__(256) void spvar_gather(
    const int*   __restrict__ idx,
    const float* __restrict__ params,
    float*       __restrict__ pvals,
    int nrows)
{
    const int t = blockIdx.x * blockDim.x + threadIdx.x;
    const int r = t * 4;
    if (r + 3 < nrows) {
        const i32x4 i4 = *(const i32x4*)(idx + r);
        f32x4 p;
        p.x = params[i4.x];
        p.y = params[i4.y];
        p.z = params[i4.z];
        p.w = params[i4.w];
        *(f32x4*)(pvals + r) = p;
    } else {
        #pragma unroll
        for (int u = 0; u < 4; ++u)
            if (r + u < nrows) pvals[r + u] = params[idx[r + u]];
    }
}

__global__ __launch_bounds__(256) void spvar_scale(
    const f32x4* __restrict__ xs4,
    const float* __restrict__ pvals,
    f32x4*       __restrict__ out4,
    int nrows)
{
    const int t = blockIdx.x * blockDim.x + threadIdx.x;
    if (t < nrows) {
        const float p = pvals[t];
        f32x4 a = xs4[2 * t];
        f32x4 b = xs4[2 * t + 1];
        a *= p;
        b *= p;
        out4[2 * t]     = a;
        out4[2 * t + 1] = b;
    }
}

// Fused fallback (round-2 structure, plain policies) if ws is too small.
__global__ __launch_bounds__(256) void spvar_fused(
    const f32x4* __restrict__ xs4,
    const int*   __restrict__ idx,
    const float* __restrict__ params,
    f32x4*       __restrict__ out4,
    int nrows)
{
    const int t = blockIdx.x * blockDim.x + threadIdx.x;
    if (t < nrows) {
        const float p = params[idx[t]];
        f32x4 a = xs4[2 * t];
        f32x4 b = xs4[2 * t + 1];
        a *= p;
        b *= p;
        out4[2 * t]     = a;
        out4[2 * t + 1] = b;
    }
}

extern "C" void kernel_launch(void* const* d_in, const int* in_sizes, int n_in,
                              void* d_out, int out_size, void* d_ws, size_t ws_size,
                              hipStream_t stream) {
    const float* xs     = (const float*)d_in[0];   // [N, 8] f32
    const int*   idx    = (const int*)d_in[1];     // [N] int32 (jax x64 off)
    const float* params = (const float*)d_in[2];   // [V, 1] f32

    const int nrows = out_size / 8;                // N (out_size is f32 ELEMENTS, D=8)
    const int block = 256;

    if (ws_size >= (size_t)nrows * sizeof(float)) {
        float* pvals = (float*)d_ws;

        const int grid1 = (nrows / 4 + block - 1) / block;
        spvar_gather<<<grid1, block, 0, stream>>>(idx, params, pvals, nrows);

        const int grid2 = (nrows + block - 1) / block;
        spvar_scale<<<grid2, block, 0, stream>>>(
            (const f32x4*)xs, pvals, (f32x4*)d_out, nrows);
    } else {
        const int grid = (nrows + block - 1) / block;
        spvar_fused<<<grid, block, 0, stream>>>(
            (const f32x4*)xs, idx, params, (f32x4*)d_out, nrows);
    }
}